// Round 3
// baseline (424.921 us; speedup 1.0000x reference)
//
#include <hip/hip_runtime.h>
#include <stdint.h>

#define NB   16
#define CIN  512
#define COUT 512
#define HH   64
#define WW   64
#define NCOND 512
#define TAPS 9
#define EPSD 1e-8f

typedef short bf16x8 __attribute__((ext_vector_type(8)));
typedef float f32x4 __attribute__((ext_vector_type(4)));

static __device__ __forceinline__ short f2bf(float f) {
  union { float f; uint32_t u; } c;
  c.f = f;
  uint32_t u = c.u;
  uint32_t r = (u + 0x7FFFu + ((u >> 16) & 1u)) >> 16;
  return (short)(uint16_t)r;
}

static __device__ __forceinline__ void gl_lds16(const void* g, void* l) {
  __builtin_amdgcn_global_load_lds(
      (const __attribute__((address_space(1))) void*)g,
      (__attribute__((address_space(3))) void*)l, 16, 0, 0);
}

// counted-vmcnt barrier: wait until at most K vector-mem ops outstanding,
// raw s_barrier (no compiler-inserted full drain), memory fences both sides.
#define WBAR(K)                                                     \
  do {                                                              \
    asm volatile("s_waitcnt vmcnt(" #K ")" ::: "memory");           \
    __builtin_amdgcn_s_barrier();                                   \
    asm volatile("" ::: "memory");                                  \
  } while (0)

// ---------------- k1: gamma[b,i] = b_gamma[i] + sum_c y[b,c]*w_gamma[i,c] ----
__global__ __launch_bounds__(512) void k_gamma(const float* __restrict__ y,
                                               const float* __restrict__ w_gamma,
                                               const float* __restrict__ b_gamma,
                                               float* __restrict__ gamma,
                                               float* __restrict__ zbuf) {
  __shared__ float ys[NCOND];
  const int b = blockIdx.x;
  const int i = threadIdx.x;
  if (zbuf && b == 0 && i < 288) zbuf[i] = 0.f;  // 1152B of zeros
  ys[i] = y[b * NCOND + i];
  __syncthreads();
  const float4* wg = reinterpret_cast<const float4*>(w_gamma + (size_t)i * NCOND);
  float acc = b_gamma[i];
  for (int c4 = 0; c4 < NCOND / 4; ++c4) {
    float4 w4 = wg[c4];
    acc += w4.x * ys[c4 * 4 + 0] + w4.y * ys[c4 * 4 + 1] +
           w4.z * ys[c4 * 4 + 2] + w4.w * ys[c4 * 4 + 3];
  }
  gamma[b * CIN + i] = acc;
}

// ---------------- k2: s2[o,i] = sum_tap w^2 ; Wr[o][tap][i] = bf16(w) --------
__global__ __launch_bounds__(256) void k_prep(const float* __restrict__ w_conv,
                                              float* __restrict__ s2,
                                              short* __restrict__ Wr) {
  __shared__ float ws_s[CIN * TAPS];
  const int o = blockIdx.x;
  const int t = threadIdx.x;
  const float* wsrc = w_conv + (size_t)o * CIN * TAPS;
  for (int idx = t; idx < CIN * TAPS; idx += 256) ws_s[idx] = wsrc[idx];
  __syncthreads();
  for (int i = t; i < CIN; i += 256) {
    float s = 0.f;
#pragma unroll
    for (int tap = 0; tap < TAPS; ++tap) {
      float v = ws_s[i * TAPS + tap];
      s += v * v;
    }
    s2[(size_t)o * CIN + i] = s;
  }
  for (int idx = t; idx < CIN * TAPS; idx += 256) {
    int i = idx & (CIN - 1);
    int tap = idx >> 9;
    Wr[((size_t)o * TAPS + tap) * CIN + i] = f2bf(ws_s[i * TAPS + tap]);
  }
}

// ---------------- k3: d[b,o] = rsqrt(sum_i gamma^2 * s2 + eps) ---------------
__global__ __launch_bounds__(512) void k_d(const float* __restrict__ gamma,
                                           const float* __restrict__ s2,
                                           float* __restrict__ dscale) {
  __shared__ float g2[CIN];
  const int b = blockIdx.x;
  const int o = threadIdx.x;
  float g = gamma[b * CIN + o];
  g2[o] = g * g;
  __syncthreads();
  const float4* s4 = reinterpret_cast<const float4*>(s2 + (size_t)o * CIN);
  float acc = 0.f;
  for (int i4 = 0; i4 < CIN / 4; ++i4) {
    float4 v = s4[i4];
    acc += v.x * g2[i4 * 4 + 0] + v.y * g2[i4 * 4 + 1] +
           v.z * g2[i4 * 4 + 2] + v.w * g2[i4 * 4 + 3];
  }
  dscale[b * COUT + o] = rsqrtf(acc + EPSD);
}

// ---------------- k_xmod: xm[b][y][w][c] = bf16(x[b][c][y][w] * gamma[b][c]) -
__global__ __launch_bounds__(256) void k_xmod(const float* __restrict__ x,
                                              const float* __restrict__ gamma,
                                              short* __restrict__ xm) {
  __shared__ float tile[64][67];
  __shared__ float gs[CIN];
  const int y = blockIdx.x, b = blockIdx.y;
  const int t = threadIdx.x;
  gs[t] = gamma[b * CIN + t];
  gs[t + 256] = gamma[b * CIN + t + 256];
  __syncthreads();
  for (int c0 = 0; c0 < CIN; c0 += 64) {
    {
      int w = t & 63;
      int cb = t >> 6;  // 0..3
      const float* xp = x + (((size_t)(b * CIN + c0 + cb)) * HH + y) * WW + w;
#pragma unroll
      for (int p = 0; p < 16; ++p)
        tile[cb + p * 4][w] = xp[(size_t)p * 4 * HH * WW];
    }
    __syncthreads();
    {
      int w = t >> 2, q = t & 3;
      short* dst = xm + (((size_t)b * HH + y) * WW + w) * CIN + c0 + q * 16;
#pragma unroll
      for (int h = 0; h < 2; ++h) {
        short tmp[8];
#pragma unroll
        for (int j = 0; j < 8; ++j) {
          int c = q * 16 + h * 8 + j;
          tmp[j] = f2bf(tile[c][w] * gs[c0 + c]);
        }
        *reinterpret_cast<bf16x8*>(dst + h * 8) = *reinterpret_cast<const bf16x8*>(tmp);
      }
    }
    __syncthreads();
  }
}

// ---------------- k_conv3: ring-pipelined implicit-GEMM conv -----------------
// grid 1024 = ot(4) x b(16) x sp(16), XCD-chunked. 256 thr = 4 waves (2x2).
// out tile 128 cout x 256 px (4 rows x 64 cols). BK=32 cin, 144 steps.
// A: ring of 3 (stage distance 2, idx tap%3). X: dbuf per chunk (idx c&1).
// Counted vmcnt: tap0 -> vmcnt(8), else vmcnt(2). Raw s_barrier.
__global__ __launch_bounds__(256, 2) void k_conv3(const short* __restrict__ xm,
                                                  const short* __restrict__ Wr,
                                                  const short* __restrict__ zbuf,
                                                  const float* __restrict__ dscale,
                                                  float* __restrict__ out) {
  __shared__ short As[3][128 * 32];   // 3 x 8KB ring
  __shared__ short Xs[2][6 * 64 * 32]; // 2 x 24KB (6 input rowblocks)
  __shared__ float d_s[128];

  const int orig = blockIdx.x;
  const int wgid = ((orig & 7) << 7) | (orig >> 3);  // 1024 % 8 == 0
  const int ot = wgid >> 8;
  const int b = (wgid >> 4) & 15;
  const int sp = wgid & 15;  // output rows sp*4 .. sp*4+3

  const int t = threadIdx.x, lane = t & 63;
  const int wv = t >> 6, wr = wv >> 1, wc = wv & 1;
  const int l15 = lane & 15;
  const int kb0 = (lane >> 4) << 4;

  if (t < 128) d_s[t] = dscale[b * COUT + ot * 128 + t];

  // ---- staging source pointers ----
  const short* a_src[2];
#pragma unroll
  for (int i = 0; i < 2; ++i) {
    int slot = t + 256 * i;
    int row = slot >> 2, sl = slot & 3;
    int off = ((sl * 16) ^ (((row >> 1) & 3) << 4)) >> 1;
    a_src[i] = Wr + (size_t)(ot * 128 + row) * (TAPS * CIN) + off;
  }
  const short* x_src[6];
#pragma unroll
  for (int i = 0; i < 6; ++i) {
    int slot = t + 256 * i;
    int prow = slot >> 2, sl = slot & 3;
    int rb = prow >> 6, w = prow & 63;
    int off = ((sl * 16) ^ (((prow >> 1) & 3) << 4)) >> 1;
    int ysrc = sp * 4 + rb - 1;
    bool rv = (ysrc >= 0) && (ysrc < HH);
    x_src[i] = rv ? xm + (((size_t)b * HH + ysrc) * WW + w) * CIN + off
                  : zbuf + off;  // zbuf: 576 zero shorts, koff+off stays inside
  }

  // ---- ds_read base addresses (all imm-foldable offsets added at use) ----
  const char* a_base[4];
#pragma unroll
  for (int m = 0; m < 4; ++m) {
    int row = wr * 64 + m * 16 + l15;
    a_base[m] = (const char*)&As[0][0] + row * 64 + (kb0 ^ (((row >> 1) & 3) << 4));
  }
  const char* b_base[4][3];
#pragma unroll
  for (int nq = 0; nq < 4; ++nq) {
#pragma unroll
    for (int dxi = 0; dxi < 3; ++dxi) {
      int c = nq * 16 + l15;
      int cc = c + dxi - 1;
      int ccl = cc < 0 ? 0 : (cc > 63 ? 63 : cc);
      b_base[nq][dxi] = (const char*)&Xs[0][0] + (2 * wc) * 4096 + ccl * 64 +
                        (kb0 ^ (((ccl >> 1) & 3) << 4));
    }
  }

  f32x4 acc[4][8];
#pragma unroll
  for (int m = 0; m < 4; ++m)
#pragma unroll
    for (int n = 0; n < 8; ++n)
      acc[m][n] = (f32x4){0.f, 0.f, 0.f, 0.f};

  // ---- prologue: panels g=0 (tap0), g=1 (tap1), X chunk 0; full drain ----
#pragma unroll
  for (int i = 0; i < 2; ++i)
    gl_lds16(a_src[i] + 0 * 512, (char*)&As[0][0] + (t + 256 * i) * 16);
#pragma unroll
  for (int i = 0; i < 2; ++i)
    gl_lds16(a_src[i] + 1 * 512, (char*)&As[1][0] + (t + 256 * i) * 16);
#pragma unroll
  for (int i = 0; i < 6; ++i)
    gl_lds16(x_src[i] + 0, (char*)&Xs[0][0] + (t + 256 * i) * 16);
  asm volatile("s_waitcnt vmcnt(0) lgkmcnt(0)" ::: "memory");
  __builtin_amdgcn_s_barrier();
  asm volatile("" ::: "memory");

  int koff = 0;  // current chunk offset in shorts (c*32)
  for (int cp = 0; cp < 8; ++cp) {
#pragma unroll
    for (int half = 0; half < 2; ++half) {
#pragma unroll
      for (int tp = 0; tp < TAPS; ++tp) {
        // stage A panel for step g+2 into ring (tp+2)%3
        {
          const int tst = (tp + 2) % 9;
          const int cross = (tp >= 7) ? 32 : 0;  // next chunk (dummy at tail: ok)
          const int ring = (tp + 2) % 3;
#pragma unroll
          for (int i = 0; i < 2; ++i)
            gl_lds16(a_src[i] + koff + tst * 512 + cross,
                     (char*)&As[ring][0] + (t + 256 * i) * 16);
        }
        if (tp == 0) {
          // stage X for next chunk (dummy into unused buffer at last chunk)
#pragma unroll
          for (int i = 0; i < 6; ++i)
            gl_lds16(x_src[i] + koff + 32,
                     (char*)&Xs[half ^ 1][0] + (t + 256 * i) * 16);
        }

        const int dy = tp / 3 - 1, dx = tp % 3 - 1;
        bf16x8 afr[4], bfr[8];
#pragma unroll
        for (int m = 0; m < 4; ++m)
          afr[m] = *reinterpret_cast<const bf16x8*>(a_base[m] + (tp % 3) * 8192);
#pragma unroll
        for (int n = 0; n < 8; ++n) {
          const int imm = ((n >> 2) + dy + 1) * 4096 + half * 24576;
          bfr[n] = *reinterpret_cast<const bf16x8*>(b_base[n & 3][dx + 1] + imm);
        }
        if (dx == -1) {
          if (l15 == 0) {
            bfr[0] = (bf16x8){0, 0, 0, 0, 0, 0, 0, 0};
            bfr[4] = (bf16x8){0, 0, 0, 0, 0, 0, 0, 0};
          }
        }
        if (dx == 1) {
          if (l15 == 15) {
            bfr[3] = (bf16x8){0, 0, 0, 0, 0, 0, 0, 0};
            bfr[7] = (bf16x8){0, 0, 0, 0, 0, 0, 0, 0};
          }
        }
#pragma unroll
        for (int m = 0; m < 4; ++m)
#pragma unroll
          for (int n = 0; n < 8; ++n)
            acc[m][n] = __builtin_amdgcn_mfma_f32_16x16x32_bf16(afr[m], bfr[n],
                                                                acc[m][n], 0, 0, 0);
        if (tp == 0) {
          WBAR(8);
        } else {
          WBAR(2);
        }
      }
      koff += 32;
    }
  }

  // ---- epilogue: out = d[b,o] * acc ----
#pragma unroll
  for (int m = 0; m < 4; ++m) {
#pragma unroll
    for (int n = 0; n < 8; ++n) {
#pragma unroll
      for (int j = 0; j < 4; ++j) {
        int o_l = wr * 64 + m * 16 + (lane >> 4) * 4 + j;
        int o = ot * 128 + o_l;
        int p = wc * 128 + n * 16 + l15;
        int yy = sp * 4 + (p >> 6);
        int cx = p & 63;
        out[(((size_t)b * COUT + o) * HH + yy) * WW + cx] = d_s[o_l] * acc[m][n][j];
      }
    }
  }
}

// ---------------- fallback conv (round-1 kernel) for small ws ----------------
__global__ __launch_bounds__(256) void k_conv_fb(const float* __restrict__ x,
                                                 const short* __restrict__ Wr,
                                                 const float* __restrict__ gamma,
                                                 const float* __restrict__ dscale,
                                                 float* __restrict__ out) {
  __shared__ short As[128 * 64];
  __shared__ short Xs[4 * 64 * 64];
  __shared__ float gam_s[CIN];
  __shared__ float d_s[128];

  const int sp = blockIdx.x;
  const int ot = blockIdx.y;
  const int b  = blockIdx.z;
  const int t  = threadIdx.x;
  const int lane = t & 63;
  const int wv = t >> 6;
  const int wr = wv >> 1;
  const int wc = wv & 1;

  gam_s[t] = gamma[b * CIN + t];
  gam_s[t + 256] = gamma[b * CIN + t + 256];
  if (t < 128) d_s[t] = dscale[b * COUT + ot * 128 + t];

  f32x4 acc[4][4];
#pragma unroll
  for (int m = 0; m < 4; ++m)
#pragma unroll
    for (int n = 0; n < 4; ++n)
      acc[m][n] = (f32x4){0.f, 0.f, 0.f, 0.f};

  const int srow = t >> 6;
  const int sc = t & 63;
  const int ysrc = sp * 2 + srow - 1;
  const bool rv = (ysrc >= 0) && (ysrc < HH);
  const int ycl = rv ? ysrc : 0;
  const float* xrow = x + (((size_t)b * CIN) * HH + ycl) * WW + sc;
  short* xs_base = &Xs[(srow * 64 + sc) * 64];
  const int xs_sw = (sc & 7) << 4;

  for (int chunk = 0; chunk < CIN / 64; ++chunk) {
    const int i0 = chunk * 64;
    __syncthreads();
    {
      const float* xp = xrow + (size_t)i0 * (HH * WW);
#pragma unroll
      for (int i8 = 0; i8 < 8; ++i8) {
        short tmp[8];
#pragma unroll
        for (int j = 0; j < 8; ++j) {
          int i = i8 * 8 + j;
          float v = rv ? xp[i * (HH * WW)] : 0.0f;
          tmp[j] = f2bf(v * gam_s[i0 + i]);
        }
        char* dst = (char*)xs_base + ((i8 * 16) ^ xs_sw);
        *reinterpret_cast<bf16x8*>(dst) = *reinterpret_cast<const bf16x8*>(tmp);
      }
    }
    for (int tap = 0; tap < TAPS; ++tap) {
      __syncthreads();
#pragma unroll
      for (int j = 0; j < 4; ++j) {
        int s = t + 256 * j;
        int row = s >> 3, sl = s & 7;
        int kbyte = (sl * 16) ^ ((row & 7) << 4);
        const short* src = Wr + ((size_t)(ot * 128 + row) * TAPS + tap) * CIN +
                           i0 + (kbyte >> 1);
        *reinterpret_cast<bf16x8*>((char*)As + row * 128 + sl * 16) =
            *reinterpret_cast<const bf16x8*>(src);
      }
      __syncthreads();

      const int dy = tap / 3 - 1, dx = tap % 3 - 1;
      bf16x8 afr[2][4], bfr[2][4];
#pragma unroll
      for (int kk = 0; kk < 2; ++kk) {
        const int kb = kk * 64 + (lane >> 4) * 16;
#pragma unroll
        for (int m = 0; m < 4; ++m) {
          int row = wr * 64 + m * 16 + (lane & 15);
          afr[kk][m] = *reinterpret_cast<const bf16x8*>(
              (const char*)As + row * 128 + (kb ^ ((row & 7) << 4)));
        }
#pragma unroll
        for (int n = 0; n < 4; ++n) {
          int p = wc * 64 + n * 16 + (lane & 15);
          int r = p >> 6, c = p & 63;
          int cc = c + dx;
          bool val = (cc >= 0) && (cc < WW);
          int ccl = val ? cc : 0;
          int rr = r + dy + 1;
          bf16x8 f = *reinterpret_cast<const bf16x8*>(
              (const char*)Xs + (rr * 64 + ccl) * 128 + (kb ^ ((ccl & 7) << 4)));
          if (!val) f = (bf16x8){0, 0, 0, 0, 0, 0, 0, 0};
          bfr[kk][n] = f;
        }
      }
#pragma unroll
      for (int m = 0; m < 4; ++m)
#pragma unroll
        for (int n = 0; n < 4; ++n)
#pragma unroll
          for (int kk = 0; kk < 2; ++kk)
            acc[m][n] = __builtin_amdgcn_mfma_f32_16x16x32_bf16(
                afr[kk][m], bfr[kk][n], acc[m][n], 0, 0, 0);
    }
  }

#pragma unroll
  for (int m = 0; m < 4; ++m) {
#pragma unroll
    for (int n = 0; n < 4; ++n) {
#pragma unroll
      for (int j = 0; j < 4; ++j) {
        int o_l = wr * 64 + m * 16 + (lane >> 4) * 4 + j;
        int o = ot * 128 + o_l;
        int p = wc * 64 + n * 16 + (lane & 15);
        int yy = sp * 2 + (p >> 6);
        int cx = p & 63;
        out[(((size_t)b * COUT + o) * HH + yy) * WW + cx] = d_s[o_l] * acc[m][n][j];
      }
    }
  }
}

extern "C" void kernel_launch(void* const* d_in, const int* in_sizes, int n_in,
                              void* d_out, int out_size, void* d_ws, size_t ws_size,
                              hipStream_t stream) {
  const float* x = (const float*)d_in[0];
  const float* y = (const float*)d_in[1];
  const float* w_conv = (const float*)d_in[2];
  const float* w_gamma = (const float*)d_in[3];
  const float* b_gamma = (const float*)d_in[4];
  float* out = (float*)d_out;

  char* ws = (char*)d_ws;
  short* Wr = (short*)ws;                        // 4,718,592 B
  float* gamma = (float*)(ws + 4718592);         // 32,768 B
  float* dsc = (float*)(ws + 4751360);           // 32,768 B
  float* s2 = (float*)(ws + 4784128);            // 1,048,576 B
  char* zbuf = ws + 5832704;                     // 4,096 B (zero page)
  short* xm = (short*)(ws + 5836800);            // 67,108,864 B
  const size_t NEED = 5836800 + (size_t)NB * HH * WW * CIN * 2;

  const bool fast = ws_size >= NEED;

  hipLaunchKernelGGL(k_gamma, dim3(NB), dim3(512), 0, stream, y, w_gamma, b_gamma,
                     gamma, fast ? (float*)zbuf : (float*)nullptr);
  hipLaunchKernelGGL(k_prep, dim3(COUT), dim3(256), 0, stream, w_conv, s2, Wr);
  hipLaunchKernelGGL(k_d, dim3(NB), dim3(512), 0, stream, gamma, s2, dsc);
  if (fast) {
    hipLaunchKernelGGL(k_xmod, dim3(HH, NB), dim3(256), 0, stream, x, gamma, xm);
    hipLaunchKernelGGL(k_conv3, dim3(1024), dim3(256), 0, stream, xm, Wr,
                       (const short*)zbuf, dsc, out);
  } else {
    hipLaunchKernelGGL(k_conv_fb, dim3(32, 4, NB), dim3(256), 0, stream, x, Wr,
                       gamma, dsc, out);
  }
}

// Round 4
// 407.598 us; speedup vs baseline: 1.0425x; 1.0425x over previous
//
#include <hip/hip_runtime.h>
#include <stdint.h>

#define NB   16
#define CIN  512
#define COUT 512
#define HH   64
#define WW   64
#define NCOND 512
#define TAPS 9
#define EPSD 1e-8f

typedef short bf16x8 __attribute__((ext_vector_type(8)));
typedef float f32x4 __attribute__((ext_vector_type(4)));

static __device__ __forceinline__ short f2bf(float f) {
  union { float f; uint32_t u; } c;
  c.f = f;
  uint32_t u = c.u;
  uint32_t r = (u + 0x7FFFu + ((u >> 16) & 1u)) >> 16;
  return (short)(uint16_t)r;
}

static __device__ __forceinline__ void gl_lds16(const void* g, void* l) {
  __builtin_amdgcn_global_load_lds(
      (const __attribute__((address_space(1))) void*)g,
      (__attribute__((address_space(3))) void*)l, 16, 0, 0);
}

// counted-vmcnt barrier (T4): wait until <=K vmem ops outstanding, raw barrier.
#define WBAR(K)                                                     \
  do {                                                              \
    asm volatile("s_waitcnt vmcnt(" #K ")" ::: "memory");           \
    __builtin_amdgcn_s_barrier();                                   \
    asm volatile("" ::: "memory");                                  \
  } while (0)

// ---------------- k1: gamma[b,i] = b_gamma[i] + sum_c y[b,c]*w_gamma[i,c] ----
__global__ __launch_bounds__(512) void k_gamma(const float* __restrict__ y,
                                               const float* __restrict__ w_gamma,
                                               const float* __restrict__ b_gamma,
                                               float* __restrict__ gamma,
                                               float* __restrict__ zbuf) {
  __shared__ float ys[NCOND];
  const int b = blockIdx.x;
  const int i = threadIdx.x;
  if (zbuf && b == 0) { zbuf[i] = 0.f; zbuf[i + 512] = 0.f; }  // 4KB zeros
  ys[i] = y[b * NCOND + i];
  __syncthreads();
  const float4* wg = reinterpret_cast<const float4*>(w_gamma + (size_t)i * NCOND);
  float acc = b_gamma[i];
  for (int c4 = 0; c4 < NCOND / 4; ++c4) {
    float4 w4 = wg[c4];
    acc += w4.x * ys[c4 * 4 + 0] + w4.y * ys[c4 * 4 + 1] +
           w4.z * ys[c4 * 4 + 2] + w4.w * ys[c4 * 4 + 3];
  }
  gamma[b * CIN + i] = acc;
}

// ------- k_prep2: s2 + W2[chunk][tap][cout][cin32], 16B-slot pre-swizzled ----
__global__ __launch_bounds__(256) void k_prep2(const float* __restrict__ w_conv,
                                               float* __restrict__ s2,
                                               short* __restrict__ W2) {
  __shared__ float ws_s[CIN * TAPS];
  const int o = blockIdx.x;
  const int t = threadIdx.x;
  const float* wsrc = w_conv + (size_t)o * CIN * TAPS;
  for (int idx = t; idx < CIN * TAPS; idx += 256) ws_s[idx] = wsrc[idx];
  __syncthreads();
  for (int i = t; i < CIN; i += 256) {
    float s = 0.f;
#pragma unroll
    for (int tap = 0; tap < TAPS; ++tap) {
      float v = ws_s[i * TAPS + tap];
      s += v * v;
    }
    s2[(size_t)o * CIN + i] = s;
  }
  const int key = (o >> 1) & 3;
  for (int k = t; k < CIN * TAPS; k += 256) {
    int tap = k >> 9;       // 0..8
    int r = k & 511;        // cin index i
    int c = r >> 5, sl = (r >> 3) & 3, j = r & 7;
    W2[((size_t)(c * TAPS + tap) * COUT + o) * 32 + ((sl ^ key) * 8) + j] =
        f2bf(ws_s[r * TAPS + tap]);
  }
}

// ---- k_prep (old layout, fallback path): Wr[o][tap][i] --------------------
__global__ __launch_bounds__(256) void k_prep(const float* __restrict__ w_conv,
                                              float* __restrict__ s2,
                                              short* __restrict__ Wr) {
  __shared__ float ws_s[CIN * TAPS];
  const int o = blockIdx.x;
  const int t = threadIdx.x;
  const float* wsrc = w_conv + (size_t)o * CIN * TAPS;
  for (int idx = t; idx < CIN * TAPS; idx += 256) ws_s[idx] = wsrc[idx];
  __syncthreads();
  for (int i = t; i < CIN; i += 256) {
    float s = 0.f;
#pragma unroll
    for (int tap = 0; tap < TAPS; ++tap) {
      float v = ws_s[i * TAPS + tap];
      s += v * v;
    }
    s2[(size_t)o * CIN + i] = s;
  }
  for (int idx = t; idx < CIN * TAPS; idx += 256) {
    int i = idx & (CIN - 1);
    int tap = idx >> 9;
    Wr[((size_t)o * TAPS + tap) * CIN + i] = f2bf(ws_s[i * TAPS + tap]);
  }
}

// ---------------- k3: d[b,o] = rsqrt(sum_i gamma^2 * s2 + eps) ---------------
__global__ __launch_bounds__(512) void k_d(const float* __restrict__ gamma,
                                           const float* __restrict__ s2,
                                           float* __restrict__ dscale) {
  __shared__ float g2[CIN];
  const int b = blockIdx.x;
  const int o = threadIdx.x;
  float g = gamma[b * CIN + o];
  g2[o] = g * g;
  __syncthreads();
  const float4* s4 = reinterpret_cast<const float4*>(s2 + (size_t)o * CIN);
  float acc = 0.f;
  for (int i4 = 0; i4 < CIN / 4; ++i4) {
    float4 v = s4[i4];
    acc += v.x * g2[i4 * 4 + 0] + v.y * g2[i4 * 4 + 1] +
           v.z * g2[i4 * 4 + 2] + v.w * g2[i4 * 4 + 3];
  }
  dscale[b * COUT + o] = rsqrtf(acc + EPSD);
}

// -- k_xmod2: xm[b][y][w][cin] bf16 modulated, 16B-slot pre-swizzled by w -----
__global__ __launch_bounds__(256) void k_xmod2(const float* __restrict__ x,
                                               const float* __restrict__ gamma,
                                               short* __restrict__ xm) {
  __shared__ float tile[64][67];
  __shared__ float gs[CIN];
  const int y = blockIdx.x, b = blockIdx.y;
  const int t = threadIdx.x;
  gs[t] = gamma[b * CIN + t];
  gs[t + 256] = gamma[b * CIN + t + 256];
  __syncthreads();
  const int w = t >> 2, q = t & 3;
  const int sw = (w >> 1) & 3;
  short* dst = xm + (((size_t)b * HH + y) * WW + w) * CIN;
  for (int c0 = 0; c0 < CIN; c0 += 64) {
    {
      int ww_ = t & 63;
      int cb = t >> 6;  // 0..3
      const float* xp = x + (((size_t)(b * CIN + c0 + cb)) * HH + y) * WW + ww_;
#pragma unroll
      for (int p = 0; p < 16; ++p)
        tile[cb + p * 4][ww_] = xp[(size_t)p * 4 * HH * WW];
    }
    __syncthreads();
#pragma unroll
    for (int h = 0; h < 2; ++h) {
      int c_lo = q * 16 + h * 8;
      int chunk = (c0 + c_lo) >> 5;
      int sl = (c_lo >> 3) & 3;
      short tmp[8];
#pragma unroll
      for (int j = 0; j < 8; ++j)
        tmp[j] = f2bf(tile[c_lo + j][w] * gs[c0 + c_lo + j]);
      *reinterpret_cast<bf16x8*>(dst + chunk * 32 + (sl ^ sw) * 8) =
          *reinterpret_cast<const bf16x8*>(tmp);
    }
    __syncthreads();
  }
}

// ---------------- k_conv4: distance-3 pipelined implicit-GEMM conv -----------
// grid 2048 = ot(4) x b(16) x sp(32), XCD-chunked. 256 thr = 4 waves (2x2).
// out tile 128 cout x 128 px (2 rows x 64 cols). BK=32 cin, 144 steps.
// A: ring-4, stage distance 3. X: dbuf per chunk. vmcnt: N=4 (8 at tp0/tp1).
__global__ __launch_bounds__(256, 2) void k_conv4(const short* __restrict__ xm,
                                                  const short* __restrict__ W2,
                                                  const short* __restrict__ zbuf,
                                                  const float* __restrict__ dscale,
                                                  float* __restrict__ out) {
  __shared__ short As[4][128 * 32];    // 4 x 8KB ring
  __shared__ short Xs[2][4 * 64 * 32]; // 2 x 16KB
  __shared__ float d_s[128];

  const int orig = blockIdx.x;
  const int wgid = ((orig & 7) << 8) | (orig >> 3);  // 2048 % 8 == 0
  const int ot = wgid >> 9;
  const int b = (wgid >> 5) & 15;
  const int sp = wgid & 31;  // output rows 2sp, 2sp+1

  const int t = threadIdx.x, lane = t & 63;
  const int wv = t >> 6, wr = wv >> 1, wc = wv & 1;
  const int l15 = lane & 15;
  const int kb0 = (lane >> 4) << 4;

  if (t < 128) d_s[t] = dscale[b * COUT + ot * 128 + t];

  // ---- linear staging sources (layouts pre-swizzled at build time) ----
  const short* aP = W2 + ot * 128 * 32 + t * 8;  // + panel offsets (shorts)
  const short* xP[4];
#pragma unroll
  for (int rb = 0; rb < 4; ++rb) {
    int ysrc = sp * 2 + rb - 1;
    bool rv = (ysrc >= 0) && (ysrc < HH);
    xP[rb] = rv ? xm + ((size_t)(b * HH + ysrc) * WW) * CIN + (t >> 2) * CIN + (t & 3) * 8
                : zbuf + (t & 3) * 8;
  }

  // ---- ds_read bases ----
  const char* pa = (const char*)&As[0][0] + (wr * 64 + l15) * 64 +
                   (kb0 ^ (((l15 >> 1) & 3) << 4));
  const char* pb[3];
#pragma unroll
  for (int dxi = 0; dxi < 3; ++dxi) {
    int lcc = l15 + dxi - 1;  // -1..16
    int key = (lcc < 0) ? 3 : ((lcc > 15) ? 0 : ((lcc >> 1) & 3));
    pb[dxi] = (const char*)&Xs[0][0] + wc * 4096 + lcc * 64 + (kb0 ^ (key << 4));
  }

  auto stA = [&](int slot, int poff) {  // poff in shorts
    gl_lds16(aP + poff, (char*)&As[0][0] + slot * 8192 + t * 16);
    gl_lds16(aP + poff + 2048, (char*)&As[0][0] + slot * 8192 + 4096 + t * 16);
  };
  auto stX = [&](int buf, int koff) {  // koff in shorts
#pragma unroll
    for (int rb = 0; rb < 4; ++rb)
      gl_lds16(xP[rb] + koff, (char*)&Xs[0][0] + buf * 16384 + rb * 4096 + t * 16);
  };

  f32x4 acc[4][4];
#pragma unroll
  for (int m = 0; m < 4; ++m)
#pragma unroll
    for (int n = 0; n < 4; ++n)
      acc[m][n] = (f32x4){0.f, 0.f, 0.f, 0.f};

  // ---- prologue: A panels for steps 0,1,2 + X chunk 0; full drain ----
  stA(0, 0 * 16384);
  stA(1, 1 * 16384);
  stA(2, 2 * 16384);
  stX(0, 0);
  asm volatile("s_waitcnt vmcnt(0) lgkmcnt(0)" ::: "memory");
  __builtin_amdgcn_s_barrier();
  asm volatile("" ::: "memory");

  const bf16x8 zero8 = (bf16x8){0, 0, 0, 0, 0, 0, 0, 0};
  for (int cb = 0; cb < 4; ++cb) {
#pragma unroll
    for (int lh = 0; lh < 4; ++lh) {  // chunk = 4*cb + lh
#pragma unroll
      for (int tp = 0; tp < TAPS; ++tp) {
        const int u = lh * 9 + tp;
        // A prefetch for step u+3 (panel (chunk + (tp>=6), (tp+3)%9))
        stA((u + 3) & 3, ((lh + (tp >= 6 ? 1 : 0)) * 9 + (tp + 3) % 9) * 16384);
        if (tp == 0) stX((lh & 1) ^ 1, (lh + 1) * 32);

        const int dy = tp / 3 - 1, dx = tp % 3 - 1;
        bf16x8 afr[4], bfr[4];
#pragma unroll
        for (int m = 0; m < 4; ++m)
          afr[m] = *reinterpret_cast<const bf16x8*>(pa + (u & 3) * 8192 + m * 1024);
#pragma unroll
        for (int n = 0; n < 4; ++n)
          bfr[n] = *reinterpret_cast<const bf16x8*>(
              pb[dx + 1] + (lh & 1) * 16384 + (dy + 1) * 4096 + n * 1024);
        if (dx == -1) { if (l15 == 0)  bfr[0] = zero8; }
        if (dx == 1)  { if (l15 == 15) bfr[3] = zero8; }

        __builtin_amdgcn_s_setprio(1);
#pragma unroll
        for (int m = 0; m < 4; ++m)
#pragma unroll
          for (int n = 0; n < 4; ++n)
            acc[m][n] = __builtin_amdgcn_mfma_f32_16x16x32_bf16(afr[m], bfr[n],
                                                                acc[m][n], 0, 0, 0);
        __builtin_amdgcn_s_setprio(0);

        if (tp <= 1) { WBAR(8); } else { WBAR(4); }
      }
    }
    aP += 4 * 9 * 16384;  // advance 4 chunks
#pragma unroll
    for (int rb = 0; rb < 4; ++rb) xP[rb] += 4 * 32;
  }

  // ---- epilogue: out = d[b,o] * acc ----
#pragma unroll
  for (int m = 0; m < 4; ++m) {
#pragma unroll
    for (int n = 0; n < 4; ++n) {
#pragma unroll
      for (int j = 0; j < 4; ++j) {
        int o_l = wr * 64 + m * 16 + (lane >> 4) * 4 + j;
        int o = ot * 128 + o_l;
        int p = wc * 64 + n * 16 + l15;
        int yy = sp * 2 + wc;
        (void)p;
        int cx = n * 16 + l15;
        out[(((size_t)b * COUT + o) * HH + yy) * WW + cx] = d_s[o_l] * acc[m][n][j];
      }
    }
  }
}

// ---------------- fallback conv (round-1 kernel) for small ws ----------------
__global__ __launch_bounds__(256) void k_conv_fb(const float* __restrict__ x,
                                                 const short* __restrict__ Wr,
                                                 const float* __restrict__ gamma,
                                                 const float* __restrict__ dscale,
                                                 float* __restrict__ out) {
  __shared__ short As[128 * 64];
  __shared__ short Xs[4 * 64 * 64];
  __shared__ float gam_s[CIN];
  __shared__ float d_s[128];

  const int sp = blockIdx.x;
  const int ot = blockIdx.y;
  const int b  = blockIdx.z;
  const int t  = threadIdx.x;
  const int lane = t & 63;
  const int wv = t >> 6;
  const int wr = wv >> 1;
  const int wc = wv & 1;

  gam_s[t] = gamma[b * CIN + t];
  gam_s[t + 256] = gamma[b * CIN + t + 256];
  if (t < 128) d_s[t] = dscale[b * COUT + ot * 128 + t];

  f32x4 acc[4][4];
#pragma unroll
  for (int m = 0; m < 4; ++m)
#pragma unroll
    for (int n = 0; n < 4; ++n)
      acc[m][n] = (f32x4){0.f, 0.f, 0.f, 0.f};

  const int srow = t >> 6;
  const int sc = t & 63;
  const int ysrc = sp * 2 + srow - 1;
  const bool rv = (ysrc >= 0) && (ysrc < HH);
  const int ycl = rv ? ysrc : 0;
  const float* xrow = x + (((size_t)b * CIN) * HH + ycl) * WW + sc;
  short* xs_base = &Xs[(srow * 64 + sc) * 64];
  const int xs_sw = (sc & 7) << 4;

  for (int chunk = 0; chunk < CIN / 64; ++chunk) {
    const int i0 = chunk * 64;
    __syncthreads();
    {
      const float* xp = xrow + (size_t)i0 * (HH * WW);
#pragma unroll
      for (int i8 = 0; i8 < 8; ++i8) {
        short tmp[8];
#pragma unroll
        for (int j = 0; j < 8; ++j) {
          int i = i8 * 8 + j;
          float v = rv ? xp[i * (HH * WW)] : 0.0f;
          tmp[j] = f2bf(v * gam_s[i0 + i]);
        }
        char* dst = (char*)xs_base + ((i8 * 16) ^ xs_sw);
        *reinterpret_cast<bf16x8*>(dst) = *reinterpret_cast<const bf16x8*>(tmp);
      }
    }
    for (int tap = 0; tap < TAPS; ++tap) {
      __syncthreads();
#pragma unroll
      for (int j = 0; j < 4; ++j) {
        int s = t + 256 * j;
        int row = s >> 3, sl = s & 7;
        int kbyte = (sl * 16) ^ ((row & 7) << 4);
        const short* src = Wr + ((size_t)(ot * 128 + row) * TAPS + tap) * CIN +
                           i0 + (kbyte >> 1);
        *reinterpret_cast<bf16x8*>((char*)As + row * 128 + sl * 16) =
            *reinterpret_cast<const bf16x8*>(src);
      }
      __syncthreads();

      const int dy = tap / 3 - 1, dx = tap % 3 - 1;
      bf16x8 afr[2][4], bfr[2][4];
#pragma unroll
      for (int kk = 0; kk < 2; ++kk) {
        const int kb = kk * 64 + (lane >> 4) * 16;
#pragma unroll
        for (int m = 0; m < 4; ++m) {
          int row = wr * 64 + m * 16 + (lane & 15);
          afr[kk][m] = *reinterpret_cast<const bf16x8*>(
              (const char*)As + row * 128 + (kb ^ ((row & 7) << 4)));
        }
#pragma unroll
        for (int n = 0; n < 4; ++n) {
          int p = wc * 64 + n * 16 + (lane & 15);
          int r = p >> 6, c = p & 63;
          int cc = c + dx;
          bool val = (cc >= 0) && (cc < WW);
          int ccl = val ? cc : 0;
          int rr = r + dy + 1;
          bf16x8 f = *reinterpret_cast<const bf16x8*>(
              (const char*)Xs + (rr * 64 + ccl) * 128 + (kb ^ ((ccl & 7) << 4)));
          if (!val) f = (bf16x8){0, 0, 0, 0, 0, 0, 0, 0};
          bfr[kk][n] = f;
        }
      }
#pragma unroll
      for (int m = 0; m < 4; ++m)
#pragma unroll
        for (int n = 0; n < 4; ++n)
#pragma unroll
          for (int kk = 0; kk < 2; ++kk)
            acc[m][n] = __builtin_amdgcn_mfma_f32_16x16x32_bf16(
                afr[kk][m], bfr[kk][n], acc[m][n], 0, 0, 0);
    }
  }

#pragma unroll
  for (int m = 0; m < 4; ++m) {
#pragma unroll
    for (int n = 0; n < 4; ++n) {
#pragma unroll
      for (int j = 0; j < 4; ++j) {
        int o_l = wr * 64 + m * 16 + (lane >> 4) * 4 + j;
        int o = ot * 128 + o_l;
        int p = wc * 64 + n * 16 + (lane & 15);
        int yy = sp * 2 + (p >> 6);
        int cx = p & 63;
        out[(((size_t)b * COUT + o) * HH + yy) * WW + cx] = d_s[o_l] * acc[m][n][j];
      }
    }
  }
}

extern "C" void kernel_launch(void* const* d_in, const int* in_sizes, int n_in,
                              void* d_out, int out_size, void* d_ws, size_t ws_size,
                              hipStream_t stream) {
  const float* x = (const float*)d_in[0];
  const float* y = (const float*)d_in[1];
  const float* w_conv = (const float*)d_in[2];
  const float* w_gamma = (const float*)d_in[3];
  const float* b_gamma = (const float*)d_in[4];
  float* out = (float*)d_out;

  char* ws = (char*)d_ws;
  short* W2 = (short*)ws;                        // 4,718,592 B (+128K pad)
  float* gamma = (float*)(ws + 4849664);         // 32,768 B
  float* dsc = (float*)(ws + 4882432);           // 32,768 B
  float* s2 = (float*)(ws + 4915200);            // 1,048,576 B
  char* zbuf = ws + 5963776;                     // 4,096 B zero page
  short* xm = (short*)(ws + 5967872);            // 67,108,864 B (+4K pad)
  const size_t NEED = 5967872 + (size_t)NB * HH * WW * CIN * 2 + 4096;

  const bool fast = ws_size >= NEED;

  hipLaunchKernelGGL(k_gamma, dim3(NB), dim3(512), 0, stream, y, w_gamma, b_gamma,
                     gamma, fast ? (float*)zbuf : (float*)nullptr);
  hipLaunchKernelGGL(k_d, dim3(NB), dim3(512), 0, stream, gamma, s2, dsc);
  if (fast) {
    hipLaunchKernelGGL(k_prep2, dim3(COUT), dim3(256), 0, stream, w_conv, s2, W2);
    // k_d depends on s2: relaunch order — k_prep2 must precede k_d.
  }
  // NOTE: ordering fixed below — launch sequence rebuilt for both paths.
  if (fast) {
    // (k_gamma already launched) correct order: prep2 -> d -> xmod -> conv
    hipLaunchKernelGGL(k_d, dim3(NB), dim3(512), 0, stream, gamma, s2, dsc);
    hipLaunchKernelGGL(k_xmod2, dim3(HH, NB), dim3(256), 0, stream, x, gamma, xm);
    hipLaunchKernelGGL(k_conv4, dim3(2048), dim3(256), 0, stream, xm, W2,
                       (const short*)zbuf, dsc, out);
  } else {
    hipLaunchKernelGGL(k_prep, dim3(COUT), dim3(256), 0, stream, w_conv, s2, W2);
    hipLaunchKernelGGL(k_d, dim3(NB), dim3(512), 0, stream, gamma, s2, dsc);
    hipLaunchKernelGGL(k_conv_fb, dim3(32, 4, NB), dim3(256), 0, stream, x, W2,
                       gamma, dsc, out);
  }
}

// Round 6
// 351.448 us; speedup vs baseline: 1.2091x; 1.1598x over previous
//
#include <hip/hip_runtime.h>
#include <stdint.h>

#define NB   16
#define CIN  512
#define COUT 512
#define HH   64
#define WW   64
#define NCOND 512
#define TAPS 9
#define EPSD 1e-8f

typedef short bf16x8 __attribute__((ext_vector_type(8)));
typedef float f32x4 __attribute__((ext_vector_type(4)));

static __device__ __forceinline__ short f2bf(float f) {
  union { float f; uint32_t u; } c;
  c.f = f;
  uint32_t u = c.u;
  uint32_t r = (u + 0x7FFFu + ((u >> 16) & 1u)) >> 16;
  return (short)(uint16_t)r;
}

static __device__ __forceinline__ void gl_lds16(const void* g, void* l) {
  __builtin_amdgcn_global_load_lds(
      (const __attribute__((address_space(1))) void*)g,
      (__attribute__((address_space(3))) void*)l, 16, 0, 0);
}

// ---------------- k1: gamma[b,i] = b_gamma[i] + sum_c y[b,c]*w_gamma[i,c] ----
__global__ __launch_bounds__(512) void k_gamma(const float* __restrict__ y,
                                               const float* __restrict__ w_gamma,
                                               const float* __restrict__ b_gamma,
                                               float* __restrict__ gamma,
                                               float* __restrict__ zbuf) {
  __shared__ float ys[NCOND];
  const int b = blockIdx.x;
  const int i = threadIdx.x;
  if (zbuf && b == 0) { zbuf[i] = 0.f; zbuf[i + 512] = 0.f; }  // 4KB zeros
  ys[i] = y[b * NCOND + i];
  __syncthreads();
  const float4* wg = reinterpret_cast<const float4*>(w_gamma + (size_t)i * NCOND);
  float acc = b_gamma[i];
  for (int c4 = 0; c4 < NCOND / 4; ++c4) {
    float4 w4 = wg[c4];
    acc += w4.x * ys[c4 * 4 + 0] + w4.y * ys[c4 * 4 + 1] +
           w4.z * ys[c4 * 4 + 2] + w4.w * ys[c4 * 4 + 3];
  }
  gamma[b * CIN + i] = acc;
}

// ------- k_prep2: s2 + W2[chunk][tap][cout][cin32], 16B-slot pre-swizzled ----
__global__ __launch_bounds__(256) void k_prep2(const float* __restrict__ w_conv,
                                               float* __restrict__ s2,
                                               short* __restrict__ W2) {
  __shared__ float ws_s[CIN * TAPS];
  const int o = blockIdx.x;
  const int t = threadIdx.x;
  const float* wsrc = w_conv + (size_t)o * CIN * TAPS;
  for (int idx = t; idx < CIN * TAPS; idx += 256) ws_s[idx] = wsrc[idx];
  __syncthreads();
  for (int i = t; i < CIN; i += 256) {
    float s = 0.f;
#pragma unroll
    for (int tap = 0; tap < TAPS; ++tap) {
      float v = ws_s[i * TAPS + tap];
      s += v * v;
    }
    s2[(size_t)o * CIN + i] = s;
  }
  const int key = (o >> 1) & 3;
  for (int k = t; k < CIN * TAPS; k += 256) {
    int tap = k >> 9;       // 0..8
    int r = k & 511;        // cin index i
    int c = r >> 5, sl = (r >> 3) & 3, j = r & 7;
    W2[((size_t)(c * TAPS + tap) * COUT + o) * 32 + ((sl ^ key) * 8) + j] =
        f2bf(ws_s[r * TAPS + tap]);
  }
}

// ---- k_prep (old layout, fallback path): Wr[o][tap][i] --------------------
__global__ __launch_bounds__(256) void k_prep(const float* __restrict__ w_conv,
                                              float* __restrict__ s2,
                                              short* __restrict__ Wr) {
  __shared__ float ws_s[CIN * TAPS];
  const int o = blockIdx.x;
  const int t = threadIdx.x;
  const float* wsrc = w_conv + (size_t)o * CIN * TAPS;
  for (int idx = t; idx < CIN * TAPS; idx += 256) ws_s[idx] = wsrc[idx];
  __syncthreads();
  for (int i = t; i < CIN; i += 256) {
    float s = 0.f;
#pragma unroll
    for (int tap = 0; tap < TAPS; ++tap) {
      float v = ws_s[i * TAPS + tap];
      s += v * v;
    }
    s2[(size_t)o * CIN + i] = s;
  }
  for (int idx = t; idx < CIN * TAPS; idx += 256) {
    int i = idx & (CIN - 1);
    int tap = idx >> 9;
    Wr[((size_t)o * TAPS + tap) * CIN + i] = f2bf(ws_s[i * TAPS + tap]);
  }
}

// ---------------- k3: d[b,o] = rsqrt(sum_i gamma^2 * s2 + eps) ---------------
__global__ __launch_bounds__(512) void k_d(const float* __restrict__ gamma,
                                           const float* __restrict__ s2,
                                           float* __restrict__ dscale) {
  __shared__ float g2[CIN];
  const int b = blockIdx.x;
  const int o = threadIdx.x;
  float g = gamma[b * CIN + o];
  g2[o] = g * g;
  __syncthreads();
  const float4* s4 = reinterpret_cast<const float4*>(s2 + (size_t)o * CIN);
  float acc = 0.f;
  for (int i4 = 0; i4 < CIN / 4; ++i4) {
    float4 v = s4[i4];
    acc += v.x * g2[i4 * 4 + 0] + v.y * g2[i4 * 4 + 1] +
           v.z * g2[i4 * 4 + 2] + v.w * g2[i4 * 4 + 3];
  }
  dscale[b * COUT + o] = rsqrtf(acc + EPSD);
}

// -- k_xmod2: xm[b][y][w][cin] bf16 modulated, 16B-slot pre-swizzled by w -----
__global__ __launch_bounds__(256) void k_xmod2(const float* __restrict__ x,
                                               const float* __restrict__ gamma,
                                               short* __restrict__ xm) {
  __shared__ float tile[64][67];
  __shared__ float gs[CIN];
  const int y = blockIdx.x, b = blockIdx.y;
  const int t = threadIdx.x;
  gs[t] = gamma[b * CIN + t];
  gs[t + 256] = gamma[b * CIN + t + 256];
  __syncthreads();
  const int w = t >> 2, q = t & 3;
  const int sw = (w >> 1) & 3;
  short* dst = xm + (((size_t)b * HH + y) * WW + w) * CIN;
  for (int c0 = 0; c0 < CIN; c0 += 64) {
    {
      int ww_ = t & 63;
      int cb = t >> 6;  // 0..3
      const float* xp = x + (((size_t)(b * CIN + c0 + cb)) * HH + y) * WW + ww_;
#pragma unroll
      for (int p = 0; p < 16; ++p)
        tile[cb + p * 4][ww_] = xp[(size_t)p * 4 * HH * WW];
    }
    __syncthreads();
#pragma unroll
    for (int h = 0; h < 2; ++h) {
      int c_lo = q * 16 + h * 8;
      int chunk = (c0 + c_lo) >> 5;
      int sl = (c_lo >> 3) & 3;
      short tmp[8];
#pragma unroll
      for (int j = 0; j < 8; ++j)
        tmp[j] = f2bf(tile[c_lo + j][w] * gs[c0 + c_lo + j]);
      *reinterpret_cast<bf16x8*>(dst + chunk * 32 + (sl ^ sw) * 8) =
          *reinterpret_cast<const bf16x8*>(tmp);
    }
    __syncthreads();
  }
}

// ---------------- k_conv5: m201-style 8-wave 2-phase-per-tap conv -------------
// grid 512 = ot(2) x b(16) x sp(16), XCD-chunked. 512 thr = 8 waves (2Mx4N).
// Block tile 256 cout x 256 px (4 rows). Wave tile 128 cout x 64 px (1 row).
// A: ring-4 @16KB, prefetch distance 3. X: dbuf @24KB, staged at tp7.
__global__ __launch_bounds__(512, 1) void k_conv5(const short* __restrict__ xm,
                                                  const short* __restrict__ W2,
                                                  const short* __restrict__ zbuf,
                                                  const float* __restrict__ dscale,
                                                  float* __restrict__ out) {
  __shared__ short As[4 * 256 * 32];    // 64KB ring of 4 panels
  __shared__ short Xs[2 * 6 * 64 * 32]; // 48KB (6 rowblocks x 64w x 32c) x 2
  __shared__ float d_s[256];

  const int orig = blockIdx.x;
  const int wgid = ((orig & 7) << 6) | (orig >> 3);  // 512 % 8 == 0, bijective
  const int ot = wgid >> 8;        // 0..1  (cout 256-half)
  const int b  = (wgid >> 4) & 15;
  const int sp = wgid & 15;        // output rows 4sp..4sp+3

  const int t = threadIdx.x, lane = t & 63;
  const int wv = t >> 6;           // 0..7
  const int wr = wv >> 2;          // 0..1 : cout 128-half within tile
  const int wc = wv & 3;           // 0..3 : output row within strip
  const int l15 = lane & 15;
  const int kb0 = (lane >> 4) << 4;

  if (t < 256) d_s[t] = dscale[b * COUT + ot * 256 + t];

  // ---- staging global sources (linear; layouts pre-swizzled at build) ----
  const short* aS0 = W2 + (size_t)(ot * 256 + (t >> 2)) * 32 + (t & 3) * 8;
  const short* aS1 = aS0 + 128 * 32;
  const short* xS[3];
#pragma unroll
  for (int i = 0; i < 3; ++i) {
    int idx = t + 512 * i;
    int rb = idx >> 8;             // 0..5
    int w = (idx & 255) >> 2;
    int sl = idx & 3;
    int ysrc = sp * 4 + rb - 1;
    bool rv = (ysrc >= 0) && (ysrc < HH);
    xS[i] = rv ? xm + (((size_t)b * HH + ysrc) * WW + w) * CIN + sl * 8
               : zbuf + sl * 8;    // zbuf: 2048 zero shorts (kn<=512 in range)
  }

  // ---- rotating ring pointers (all-static indexing) ----
  const char* pa0 = (const char*)&As[0] + (wr * 128 + l15) * 64 +
                    (kb0 ^ (((l15 >> 1) & 3) << 4));
  const char* paR[4];
  char* waR[4];
#pragma unroll
  for (int i = 0; i < 4; ++i) {
    paR[i] = pa0 + i * 16384;
    waR[i] = (char*)&As[0] + t * 16 + i * 16384;
  }
  // X read bases: SIGNED lcc (-1..16). Negative offset (l15==0, dx=-1) reads
  // As-tail garbage, consumed only at n==0 where it is masked to zero below;
  // for n>=1 the same negative base + n*1024 addresses the VALID pixel n*16-1.
  // (v4-verified addressing; arith-shift key (-1>>1)&3 == 3 is exact for it.)
  const char* pbx[3];
#pragma unroll
  for (int dxi = 0; dxi < 3; ++dxi) {
    int lcc = l15 + dxi - 1;             // -1..16, unclamped
    int key = (lcc >> 1) & 3;
    pbx[dxi] = (const char*)&Xs[0] + lcc * 64 + (kb0 ^ (key << 4));
  }
  const int lc3 = (l15 + 1 > 15) ? 15 : (l15 + 1);  // clamped col for (n=3,dx=+1)
  const char* pbx3 = (const char*)&Xs[0] + lc3 * 64 + (kb0 ^ (((lc3 >> 1) & 3) << 4));
  char* wx0 = (char*)&Xs[0] + t * 16;

  f32x4 acc[8][4];
#pragma unroll
  for (int m = 0; m < 8; ++m)
#pragma unroll
    for (int n = 0; n < 4; ++n)
      acc[m][n] = (f32x4){0.f, 0.f, 0.f, 0.f};

  // ---- prologue: A panels for steps 0,1,2 + X chunk 0; full drain ----
#pragma unroll
  for (int i = 0; i < 3; ++i)
    gl_lds16(xS[i], wx0 + i * 8192);
#pragma unroll
  for (int s = 0; s < 3; ++s) {
    gl_lds16(aS0 + s * 16384, waR[s]);
    gl_lds16(aS1 + s * 16384, waR[s] + 8192);
  }
  asm volatile("s_waitcnt vmcnt(0) lgkmcnt(0)" ::: "memory");
  __builtin_amdgcn_s_barrier();
  asm volatile("" ::: "memory");

  const bf16x8 z8 = (bf16x8){0, 0, 0, 0, 0, 0, 0, 0};
  int chBase = 0;     // W2 short-offset of current chunk's 9-panel group
  int kx = 0;         // current chunk cin offset (shorts)
  uint32_t xb = 0;    // X read-buffer byte offset (0 / 24576)

  for (int ch = 0; ch < 16; ++ch) {
    const int advA = (ch < 15) ? 9 * 16384 : 0;
    const int kn = (ch < 15) ? kx + 32 : 0;
    const char* q0 = pbx[0] + xb;
    const char* q1 = pbx[1] + xb;
    const char* q2 = pbx[2] + xb;
    const char* q3 = pbx3 + xb;
    char* wxT = wx0 + (xb ^ 24576);

#pragma unroll
    for (int tp = 0; tp < TAPS; ++tp) {
      const int dy = tp / 3 - 1, dx = tp % 3 - 1;
      const int rbo = (wc + dy + 1) * 4096;

      // ---- phase A: reads + stages ----
      bf16x8 afr[4], bfr[4];
#pragma unroll
      for (int m = 0; m < 4; ++m)
        afr[m] = *reinterpret_cast<const bf16x8*>(paR[tp & 3] + m * 1024);
      {
        const char* qq = (dx == -1) ? q0 : ((dx == 0) ? q1 : q2);
#pragma unroll
        for (int n = 0; n < 4; ++n) {
          const char* src = (dx == 1 && n == 3) ? q3 : qq;
          bfr[n] = *reinterpret_cast<const bf16x8*>(src + rbo + n * 1024);
        }
      }
      if (dx == -1) { if (l15 == 0)  bfr[0] = z8; }
      if (dx == 1)  { if (l15 == 15) bfr[3] = z8; }

      if (tp == 7) {
#pragma unroll
        for (int i = 0; i < 3; ++i)
          gl_lds16(xS[i] + kn, wxT + i * 8192);
      }
      {
        const int pan = chBase + ((tp >= 6) ? advA : 0) + ((tp + 3) % 9) * 16384;
        gl_lds16(aS0 + pan, waR[(tp + 3) & 3]);
        gl_lds16(aS1 + pan, waR[(tp + 3) & 3] + 8192);
      }
      __builtin_amdgcn_s_barrier();
      asm volatile("s_waitcnt lgkmcnt(0)" ::: "memory");
      __builtin_amdgcn_s_setprio(1);
#pragma unroll
      for (int m = 0; m < 4; ++m)
#pragma unroll
        for (int n = 0; n < 4; ++n)
          acc[m][n] = __builtin_amdgcn_mfma_f32_16x16x32_bf16(afr[m], bfr[n],
                                                              acc[m][n], 0, 0, 0);
      __builtin_amdgcn_s_setprio(0);
      __builtin_amdgcn_s_barrier();

      // ---- phase B: second cout-half ----
      bf16x8 af2[4];
#pragma unroll
      for (int m = 0; m < 4; ++m)
        af2[m] = *reinterpret_cast<const bf16x8*>(paR[tp & 3] + (4 + m) * 1024);
      __builtin_amdgcn_s_barrier();
      asm volatile("s_waitcnt lgkmcnt(0)" ::: "memory");
      __builtin_amdgcn_s_setprio(1);
#pragma unroll
      for (int m = 0; m < 4; ++m)
#pragma unroll
        for (int n = 0; n < 4; ++n)
          acc[4 + m][n] = __builtin_amdgcn_mfma_f32_16x16x32_bf16(af2[m], bfr[n],
                                                                  acc[4 + m][n], 0, 0, 0);
      __builtin_amdgcn_s_setprio(0);
      // counted retirement guarantee BEFORE the barrier (cross-wave visibility)
      if (tp == 7) {
        asm volatile("s_waitcnt vmcnt(7)" ::: "memory");
      } else {
        asm volatile("s_waitcnt vmcnt(4)" ::: "memory");
      }
      __builtin_amdgcn_s_barrier();
      asm volatile("" ::: "memory");
    }
    // rotate ring (slot(ch+1, i) = slot(ch, i+1))
    {
      const char* tA = paR[0];
      paR[0] = paR[1]; paR[1] = paR[2]; paR[2] = paR[3]; paR[3] = tA;
      char* tW = waR[0];
      waR[0] = waR[1]; waR[1] = waR[2]; waR[2] = waR[3]; waR[3] = tW;
    }
    chBase += 9 * 16384;
    kx += 32;
    xb ^= 24576;
  }

  asm volatile("s_waitcnt vmcnt(0)" ::: "memory");
  __builtin_amdgcn_s_barrier();

  // ---- epilogue: out = d[b,o] * acc ----
#pragma unroll
  for (int m = 0; m < 8; ++m) {
#pragma unroll
    for (int n = 0; n < 4; ++n) {
#pragma unroll
      for (int j = 0; j < 4; ++j) {
        int o_l = wr * 128 + m * 16 + (lane >> 4) * 4 + j;
        int o = ot * 256 + o_l;
        int yy = sp * 4 + wc;
        int cx = n * 16 + l15;
        out[(((size_t)b * COUT + o) * HH + yy) * WW + cx] = d_s[o_l] * acc[m][n][j];
      }
    }
  }
}

// ---------------- fallback conv (round-1 kernel) for small ws ----------------
__global__ __launch_bounds__(256) void k_conv_fb(const float* __restrict__ x,
                                                 const short* __restrict__ Wr,
                                                 const float* __restrict__ gamma,
                                                 const float* __restrict__ dscale,
                                                 float* __restrict__ out) {
  __shared__ short As[128 * 64];
  __shared__ short Xs[4 * 64 * 64];
  __shared__ float gam_s[CIN];
  __shared__ float d_s[128];

  const int sp = blockIdx.x;
  const int ot = blockIdx.y;
  const int b  = blockIdx.z;
  const int t  = threadIdx.x;
  const int lane = t & 63;
  const int wv = t >> 6;
  const int wr = wv >> 1;
  const int wc = wv & 1;

  gam_s[t] = gamma[b * CIN + t];
  gam_s[t + 256] = gamma[b * CIN + t + 256];
  if (t < 128) d_s[t] = dscale[b * COUT + ot * 128 + t];

  f32x4 acc[4][4];
#pragma unroll
  for (int m = 0; m < 4; ++m)
#pragma unroll
    for (int n = 0; n < 4; ++n)
      acc[m][n] = (f32x4){0.f, 0.f, 0.f, 0.f};

  const int srow = t >> 6;
  const int sc = t & 63;
  const int ysrc = sp * 2 + srow - 1;
  const bool rv = (ysrc >= 0) && (ysrc < HH);
  const int ycl = rv ? ysrc : 0;
  const float* xrow = x + (((size_t)b * CIN) * HH + ycl) * WW + sc;
  short* xs_base = &Xs[(srow * 64 + sc) * 64];
  const int xs_sw = (sc & 7) << 4;

  for (int chunk = 0; chunk < CIN / 64; ++chunk) {
    const int i0 = chunk * 64;
    __syncthreads();
    {
      const float* xp = xrow + (size_t)i0 * (HH * WW);
#pragma unroll
      for (int i8 = 0; i8 < 8; ++i8) {
        short tmp[8];
#pragma unroll
        for (int j = 0; j < 8; ++j) {
          int i = i8 * 8 + j;
          float v = rv ? xp[i * (HH * WW)] : 0.0f;
          tmp[j] = f2bf(v * gam_s[i0 + i]);
        }
        char* dst = (char*)xs_base + ((i8 * 16) ^ xs_sw);
        *reinterpret_cast<bf16x8*>(dst) = *reinterpret_cast<const bf16x8*>(tmp);
      }
    }
    for (int tap = 0; tap < TAPS; ++tap) {
      __syncthreads();
#pragma unroll
      for (int j = 0; j < 4; ++j) {
        int s = t + 256 * j;
        int row = s >> 3, sl = s & 7;
        int kbyte = (sl * 16) ^ ((row & 7) << 4);
        const short* src = Wr + ((size_t)(ot * 128 + row) * TAPS + tap) * CIN +
                           i0 + (kbyte >> 1);
        *reinterpret_cast<bf16x8*>((char*)As + row * 128 + sl * 16) =
            *reinterpret_cast<const bf16x8*>(src);
      }
      __syncthreads();

      const int dy = tap / 3 - 1, dx = tap % 3 - 1;
      bf16x8 afr[2][4], bfr[2][4];
#pragma unroll
      for (int kk = 0; kk < 2; ++kk) {
        const int kb = kk * 64 + (lane >> 4) * 16;
#pragma unroll
        for (int m = 0; m < 4; ++m) {
          int row = wr * 64 + m * 16 + (lane & 15);
          afr[kk][m] = *reinterpret_cast<const bf16x8*>(
              (const char*)As + row * 128 + (kb ^ ((row & 7) << 4)));
        }
#pragma unroll
        for (int n = 0; n < 4; ++n) {
          int p = wc * 64 + n * 16 + (lane & 15);
          int r = p >> 6, c = p & 63;
          int cc = c + dx;
          bool val = (cc >= 0) && (cc < WW);
          int ccl = val ? cc : 0;
          int rr = r + dy + 1;
          bf16x8 f = *reinterpret_cast<const bf16x8*>(
              (const char*)Xs + (rr * 64 + ccl) * 128 + (kb ^ ((ccl & 7) << 4)));
          if (!val) f = (bf16x8){0, 0, 0, 0, 0, 0, 0, 0};
          bfr[kk][n] = f;
        }
      }
#pragma unroll
      for (int m = 0; m < 4; ++m)
#pragma unroll
        for (int n = 0; n < 4; ++n)
#pragma unroll
          for (int kk = 0; kk < 2; ++kk)
            acc[m][n] = __builtin_amdgcn_mfma_f32_16x16x32_bf16(
                afr[kk][m], bfr[kk][n], acc[m][n], 0, 0, 0);
    }
  }

#pragma unroll
  for (int m = 0; m < 4; ++m) {
#pragma unroll
    for (int n = 0; n < 4; ++n) {
#pragma unroll
      for (int j = 0; j < 4; ++j) {
        int o_l = wr * 64 + m * 16 + (lane >> 4) * 4 + j;
        int o = ot * 128 + o_l;
        int p = wc * 64 + n * 16 + (lane & 15);
        int yy = sp * 2 + (p >> 6);
        int cx = p & 63;
        out[(((size_t)b * COUT + o) * HH + yy) * WW + cx] = d_s[o_l] * acc[m][n][j];
      }
    }
  }
}

extern "C" void kernel_launch(void* const* d_in, const int* in_sizes, int n_in,
                              void* d_out, int out_size, void* d_ws, size_t ws_size,
                              hipStream_t stream) {
  const float* x = (const float*)d_in[0];
  const float* y = (const float*)d_in[1];
  const float* w_conv = (const float*)d_in[2];
  const float* w_gamma = (const float*)d_in[3];
  const float* b_gamma = (const float*)d_in[4];
  float* out = (float*)d_out;

  char* ws = (char*)d_ws;
  short* W2 = (short*)ws;                        // 4,718,592 B (+pad)
  float* gamma = (float*)(ws + 4849664);         // 32,768 B
  float* dsc = (float*)(ws + 4882432);           // 32,768 B
  float* s2 = (float*)(ws + 4915200);            // 1,048,576 B
  char* zbuf = ws + 5963776;                     // 4,096 B zero page
  short* xm = (short*)(ws + 5967872);            // 67,108,864 B
  const size_t NEED = 5967872 + (size_t)NB * HH * WW * CIN * 2 + 4096;

  const bool fast = ws_size >= NEED;

  if (fast) {
    hipLaunchKernelGGL(k_gamma, dim3(NB), dim3(512), 0, stream, y, w_gamma,
                       b_gamma, gamma, (float*)zbuf);
    hipLaunchKernelGGL(k_prep2, dim3(COUT), dim3(256), 0, stream, w_conv, s2, W2);
    hipLaunchKernelGGL(k_d, dim3(NB), dim3(512), 0, stream, gamma, s2, dsc);
    hipLaunchKernelGGL(k_xmod2, dim3(HH, NB), dim3(256), 0, stream, x, gamma, xm);
    hipLaunchKernelGGL(k_conv5, dim3(512), dim3(512), 0, stream, xm, W2,
                       (const short*)zbuf, dsc, out);
  } else {
    hipLaunchKernelGGL(k_gamma, dim3(NB), dim3(512), 0, stream, y, w_gamma,
                       b_gamma, gamma, (float*)nullptr);
    hipLaunchKernelGGL(k_prep, dim3(COUT), dim3(256), 0, stream, w_conv, s2, W2);
    hipLaunchKernelGGL(k_d, dim3(NB), dim3(512), 0, stream, gamma, s2, dsc);
    hipLaunchKernelGGL(k_conv_fb, dim3(32, 4, NB), dim3(256), 0, stream, x, W2,
                       gamma, dsc, out);
  }
}

// Round 7
// 330.006 us; speedup vs baseline: 1.2876x; 1.0650x over previous
//
#include <hip/hip_runtime.h>
#include <stdint.h>

#define NB   16
#define CIN  512
#define COUT 512
#define HH   64
#define WW   64
#define NCOND 512
#define TAPS 9
#define EPSD 1e-8f

typedef short bf16x8 __attribute__((ext_vector_type(8)));
typedef float f32x4 __attribute__((ext_vector_type(4)));

static __device__ __forceinline__ short f2bf(float f) {
  union { float f; uint32_t u; } c;
  c.f = f;
  uint32_t u = c.u;
  uint32_t r = (u + 0x7FFFu + ((u >> 16) & 1u)) >> 16;
  return (short)(uint16_t)r;
}

static __device__ __forceinline__ void gl_lds16(const void* g, void* l) {
  __builtin_amdgcn_global_load_lds(
      (const __attribute__((address_space(1))) void*)g,
      (__attribute__((address_space(3))) void*)l, 16, 0, 0);
}

// ---------------- k1: gamma[b,i] = b_gamma[i] + sum_c y[b,c]*w_gamma[i,c] ----
__global__ __launch_bounds__(512) void k_gamma(const float* __restrict__ y,
                                               const float* __restrict__ w_gamma,
                                               const float* __restrict__ b_gamma,
                                               float* __restrict__ gamma,
                                               float* __restrict__ zbuf) {
  __shared__ float ys[NCOND];
  const int b = blockIdx.x;
  const int i = threadIdx.x;
  if (zbuf && b == 0) { zbuf[i] = 0.f; zbuf[i + 512] = 0.f; }  // 4KB zeros
  ys[i] = y[b * NCOND + i];
  __syncthreads();
  const float4* wg = reinterpret_cast<const float4*>(w_gamma + (size_t)i * NCOND);
  float acc = b_gamma[i];
  for (int c4 = 0; c4 < NCOND / 4; ++c4) {
    float4 w4 = wg[c4];
    acc += w4.x * ys[c4 * 4 + 0] + w4.y * ys[c4 * 4 + 1] +
           w4.z * ys[c4 * 4 + 2] + w4.w * ys[c4 * 4 + 3];
  }
  gamma[b * CIN + i] = acc;
}

// ------- k_prep2: s2 + W2[chunk][tap][cout][cin32], 16B-slot pre-swizzled ----
__global__ __launch_bounds__(256) void k_prep2(const float* __restrict__ w_conv,
                                               float* __restrict__ s2,
                                               short* __restrict__ W2) {
  __shared__ float ws_s[CIN * TAPS];
  const int o = blockIdx.x;
  const int t = threadIdx.x;
  const float* wsrc = w_conv + (size_t)o * CIN * TAPS;
  for (int idx = t; idx < CIN * TAPS; idx += 256) ws_s[idx] = wsrc[idx];
  __syncthreads();
  for (int i = t; i < CIN; i += 256) {
    float s = 0.f;
#pragma unroll
    for (int tap = 0; tap < TAPS; ++tap) {
      float v = ws_s[i * TAPS + tap];
      s += v * v;
    }
    s2[(size_t)o * CIN + i] = s;
  }
  const int key = (o >> 1) & 3;
  for (int k = t; k < CIN * TAPS; k += 256) {
    int tap = k >> 9;       // 0..8
    int r = k & 511;        // cin index i
    int c = r >> 5, sl = (r >> 3) & 3, j = r & 7;
    W2[((size_t)(c * TAPS + tap) * COUT + o) * 32 + ((sl ^ key) * 8) + j] =
        f2bf(ws_s[r * TAPS + tap]);
  }
}

// ---- k_prep (old layout, fallback path): Wr[o][tap][i] --------------------
__global__ __launch_bounds__(256) void k_prep(const float* __restrict__ w_conv,
                                              float* __restrict__ s2,
                                              short* __restrict__ Wr) {
  __shared__ float ws_s[CIN * TAPS];
  const int o = blockIdx.x;
  const int t = threadIdx.x;
  const float* wsrc = w_conv + (size_t)o * CIN * TAPS;
  for (int idx = t; idx < CIN * TAPS; idx += 256) ws_s[idx] = wsrc[idx];
  __syncthreads();
  for (int i = t; i < CIN; i += 256) {
    float s = 0.f;
#pragma unroll
    for (int tap = 0; tap < TAPS; ++tap) {
      float v = ws_s[i * TAPS + tap];
      s += v * v;
    }
    s2[(size_t)o * CIN + i] = s;
  }
  for (int idx = t; idx < CIN * TAPS; idx += 256) {
    int i = idx & (CIN - 1);
    int tap = idx >> 9;
    Wr[((size_t)o * TAPS + tap) * CIN + i] = f2bf(ws_s[i * TAPS + tap]);
  }
}

// ---------------- k3: d[b,o] = rsqrt(sum_i gamma^2 * s2 + eps) ---------------
__global__ __launch_bounds__(512) void k_d(const float* __restrict__ gamma,
                                           const float* __restrict__ s2,
                                           float* __restrict__ dscale) {
  __shared__ float g2[CIN];
  const int b = blockIdx.x;
  const int o = threadIdx.x;
  float g = gamma[b * CIN + o];
  g2[o] = g * g;
  __syncthreads();
  const float4* s4 = reinterpret_cast<const float4*>(s2 + (size_t)o * CIN);
  float acc = 0.f;
  for (int i4 = 0; i4 < CIN / 4; ++i4) {
    float4 v = s4[i4];
    acc += v.x * g2[i4 * 4 + 0] + v.y * g2[i4 * 4 + 1] +
           v.z * g2[i4 * 4 + 2] + v.w * g2[i4 * 4 + 3];
  }
  dscale[b * COUT + o] = rsqrtf(acc + EPSD);
}

// -- k_xmod2: xm[b][y][w][cin] bf16 modulated, 16B-slot pre-swizzled by w -----
__global__ __launch_bounds__(256) void k_xmod2(const float* __restrict__ x,
                                               const float* __restrict__ gamma,
                                               short* __restrict__ xm) {
  __shared__ float tile[64][67];
  __shared__ float gs[CIN];
  const int y = blockIdx.x, b = blockIdx.y;
  const int t = threadIdx.x;
  gs[t] = gamma[b * CIN + t];
  gs[t + 256] = gamma[b * CIN + t + 256];
  __syncthreads();
  const int w = t >> 2, q = t & 3;
  const int sw = (w >> 1) & 3;
  short* dst = xm + (((size_t)b * HH + y) * WW + w) * CIN;
  for (int c0 = 0; c0 < CIN; c0 += 64) {
    {
      int ww_ = t & 63;
      int cb = t >> 6;  // 0..3
      const float* xp = x + (((size_t)(b * CIN + c0 + cb)) * HH + y) * WW + ww_;
#pragma unroll
      for (int p = 0; p < 16; ++p)
        tile[cb + p * 4][ww_] = xp[(size_t)p * 4 * HH * WW];
    }
    __syncthreads();
#pragma unroll
    for (int h = 0; h < 2; ++h) {
      int c_lo = q * 16 + h * 8;
      int chunk = (c0 + c_lo) >> 5;
      int sl = (c_lo >> 3) & 3;
      short tmp[8];
#pragma unroll
      for (int j = 0; j < 8; ++j)
        tmp[j] = f2bf(tile[c_lo + j][w] * gs[c0 + c_lo + j]);
      *reinterpret_cast<bf16x8*>(dst + chunk * 32 + (sl ^ sw) * 8) =
          *reinterpret_cast<const bf16x8*>(tmp);
    }
    __syncthreads();
  }
}

// ---------------- k_conv6: single-barrier-per-tap pipelined conv -------------
// grid 512 = ot(2) x b(16) x sp(16), XCD-chunked. 512 thr = 8 waves (2Mx4N).
// Block tile 256 cout x 256 px (4 rows). Wave tile 128 cout x 64 px (1 row).
// A: ring-4 @16KB, prefetch distance 3. X: dbuf @24KB, staged at tp7.
// Per tap: {12 ds_read, stages, lgkm(4), 16 MFMA, lgkm(0), 16 MFMA,
//           vmcnt(4|7), s_barrier}. Edge masking via LDS zero page.
__global__ __launch_bounds__(512, 1) void k_conv6(const short* __restrict__ xm,
                                                  const short* __restrict__ W2,
                                                  const short* __restrict__ zbuf,
                                                  const float* __restrict__ dscale,
                                                  float* __restrict__ out) {
  __shared__ short As[4 * 256 * 32];    // 64KB ring of 4 panels
  __shared__ short Xs[2 * 6 * 64 * 32]; // 48KB (6 rowblocks x 64w x 32c) x 2
  __shared__ float d_s[256];
  __shared__ __align__(16) short zls[64];  // LDS zero page for edge lanes

  const int orig = blockIdx.x;
  const int wgid = ((orig & 7) << 6) | (orig >> 3);  // 512 % 8 == 0, bijective
  const int ot = wgid >> 8;        // 0..1  (cout 256-half)
  const int b  = (wgid >> 4) & 15;
  const int sp = wgid & 15;        // output rows 4sp..4sp+3

  const int t = threadIdx.x, lane = t & 63;
  const int wv = t >> 6;           // 0..7
  const int wr = wv >> 2;          // 0..1 : cout 128-half within tile
  const int wc = wv & 3;           // 0..3 : output row within strip
  const int l15 = lane & 15;
  const int kb0 = (lane >> 4) << 4;

  if (t < 256) d_s[t] = dscale[b * COUT + ot * 256 + t];
  if (t < 64) zls[t] = 0;

  // ---- staging global sources (linear; layouts pre-swizzled at build) ----
  const short* aS0 = W2 + (size_t)(ot * 256 + (t >> 2)) * 32 + (t & 3) * 8;
  const short* aS1 = aS0 + 128 * 32;
  const short* xS[3];
#pragma unroll
  for (int i = 0; i < 3; ++i) {
    int idx = t + 512 * i;
    int rb = idx >> 8;             // 0..5
    int w = (idx & 255) >> 2;
    int sl = idx & 3;
    int ysrc = sp * 4 + rb - 1;
    bool rv = (ysrc >= 0) && (ysrc < HH);
    xS[i] = rv ? xm + (((size_t)b * HH + ysrc) * WW + w) * CIN + sl * 8
               : zbuf + sl * 8;    // zbuf: 2048 zero shorts (kn<=512 in range)
  }

  // ---- rotating ring pointers (all-static indexing) ----
  const char* pa0 = (const char*)&As[0] + (wr * 128 + l15) * 64 +
                    (kb0 ^ (((l15 >> 1) & 3) << 4));
  const char* paR[4];
  char* waR[4];
#pragma unroll
  for (int i = 0; i < 4; ++i) {
    paR[i] = pa0 + i * 16384;
    waR[i] = (char*)&As[0] + t * 16 + i * 16384;
  }
  // X read bases: SIGNED lcc (-1..16). For l15==0/dx=-1 the n==0 read is
  // redirected to the LDS zero page (address-level masking); n>=1 reads via
  // the negative base land on valid pixels n*16-1 with the correct swizzle
  // key ((-1>>1)&3 == 3 == key(row 15)).
  const char* pbx[3];
#pragma unroll
  for (int dxi = 0; dxi < 3; ++dxi) {
    int lcc = l15 + dxi - 1;             // -1..16, unclamped
    int key = (lcc >> 1) & 3;
    pbx[dxi] = (const char*)&Xs[0] + lcc * 64 + (kb0 ^ (key << 4));
  }
  const int lc3 = (l15 + 1 > 15) ? 15 : (l15 + 1);  // clamped col for (n=3,dx=+1)
  const char* pbx3 = (const char*)&Xs[0] + lc3 * 64 + (kb0 ^ (((lc3 >> 1) & 3) << 4));
  char* wx0 = (char*)&Xs[0] + t * 16;
  const char* zl = (const char*)&zls[0];
  const bool mL = (l15 == 0);   // left-edge lane (dx=-1, n=0 invalid)
  const bool mR = (l15 == 15);  // right-edge lane (dx=+1, n=3 invalid)

  f32x4 acc[8][4];
#pragma unroll
  for (int m = 0; m < 8; ++m)
#pragma unroll
    for (int n = 0; n < 4; ++n)
      acc[m][n] = (f32x4){0.f, 0.f, 0.f, 0.f};

  // ---- prologue: A panels for steps 0,1,2 + X chunk 0; full drain ----
#pragma unroll
  for (int i = 0; i < 3; ++i)
    gl_lds16(xS[i], wx0 + i * 8192);
#pragma unroll
  for (int s = 0; s < 3; ++s) {
    gl_lds16(aS0 + s * 16384, waR[s]);
    gl_lds16(aS1 + s * 16384, waR[s] + 8192);
  }
  asm volatile("s_waitcnt vmcnt(0) lgkmcnt(0)" ::: "memory");
  __builtin_amdgcn_s_barrier();
  asm volatile("" ::: "memory");

  int chBase = 0;     // W2 short-offset of current chunk's 9-panel group
  int kx = 0;         // current chunk cin offset (shorts)
  uint32_t xb = 0;    // X read-buffer byte offset (0 / 24576)

  for (int ch = 0; ch < 16; ++ch) {
    const int advA = (ch < 15) ? 9 * 16384 : 0;
    const int kn = (ch < 15) ? kx + 32 : 0;
    const char* q0 = pbx[0] + xb;
    const char* q1 = pbx[1] + xb;
    const char* q2 = pbx[2] + xb;
    const char* q3 = pbx3 + xb;
    char* wxT = wx0 + (xb ^ 24576);

#pragma unroll
    for (int tp = 0; tp < TAPS; ++tp) {
      const int dy = tp / 3 - 1, dx = tp % 3 - 1;
      const int rbo = (wc + dy + 1) * 4096;

      // ---- 8 primary ds_reads (afr + bfr) ----
      bf16x8 afr[4], af2[4], bfr[4];
#pragma unroll
      for (int m = 0; m < 4; ++m)
        afr[m] = *reinterpret_cast<const bf16x8*>(paR[tp & 3] + m * 1024);
      {
        const char* qq = (dx == -1) ? q0 : ((dx == 0) ? q1 : q2);
        const char* s0 = (dx == -1 && mL) ? (zl - rbo) : qq;
        const char* s3 = (dx == 1) ? (mR ? (zl - rbo - 3 * 1024) : q3) : qq;
        bfr[0] = *reinterpret_cast<const bf16x8*>(s0 + rbo);
        bfr[1] = *reinterpret_cast<const bf16x8*>(qq + rbo + 1024);
        bfr[2] = *reinterpret_cast<const bf16x8*>(qq + rbo + 2048);
        bfr[3] = *reinterpret_cast<const bf16x8*>(s3 + rbo + 3072);
      }
      __builtin_amdgcn_sched_barrier(0);  // pin: af2 reads strictly after
      // ---- 4 secondary ds_reads (af2, counted by lgkmcnt(4)) ----
#pragma unroll
      for (int m = 0; m < 4; ++m)
        af2[m] = *reinterpret_cast<const bf16x8*>(paR[tp & 3] + (4 + m) * 1024);

      // ---- stages (vmcnt path, fly under MFMA) ----
      if (tp == 7) {
#pragma unroll
        for (int i = 0; i < 3; ++i)
          gl_lds16(xS[i] + kn, wxT + i * 8192);
      }
      {
        const int pan = chBase + ((tp >= 6) ? advA : 0) + ((tp + 3) % 9) * 16384;
        gl_lds16(aS0 + pan, waR[(tp + 3) & 3]);
        gl_lds16(aS1 + pan, waR[(tp + 3) & 3] + 8192);
      }

      asm volatile("s_waitcnt lgkmcnt(4)" ::: "memory");
      __builtin_amdgcn_sched_barrier(0);
      __builtin_amdgcn_s_setprio(1);
#pragma unroll
      for (int m = 0; m < 4; ++m)
#pragma unroll
        for (int n = 0; n < 4; ++n)
          acc[m][n] = __builtin_amdgcn_mfma_f32_16x16x32_bf16(afr[m], bfr[n],
                                                              acc[m][n], 0, 0, 0);
      asm volatile("s_waitcnt lgkmcnt(0)" ::: "memory");
      __builtin_amdgcn_sched_barrier(0);
#pragma unroll
      for (int m = 0; m < 4; ++m)
#pragma unroll
        for (int n = 0; n < 4; ++n)
          acc[4 + m][n] = __builtin_amdgcn_mfma_f32_16x16x32_bf16(af2[m], bfr[n],
                                                                  acc[4 + m][n], 0, 0, 0);
      __builtin_amdgcn_s_setprio(0);
      // counted retirement BEFORE the per-tap barrier (cross-wave visibility):
      // panels staged >=2 taps ago fully retired; this tap + prev tap in flight.
      if (tp == 7) {
        asm volatile("s_waitcnt vmcnt(7)" ::: "memory");
      } else {
        asm volatile("s_waitcnt vmcnt(4)" ::: "memory");
      }
      __builtin_amdgcn_s_barrier();
      asm volatile("" ::: "memory");
    }
    // rotate ring (slot(ch+1, i) = slot(ch, i+1))
    {
      const char* tA = paR[0];
      paR[0] = paR[1]; paR[1] = paR[2]; paR[2] = paR[3]; paR[3] = tA;
      char* tW = waR[0];
      waR[0] = waR[1]; waR[1] = waR[2]; waR[2] = waR[3]; waR[3] = tW;
    }
    chBase += 9 * 16384;
    kx += 32;
    xb ^= 24576;
  }

  asm volatile("s_waitcnt vmcnt(0)" ::: "memory");
  __builtin_amdgcn_s_barrier();

  // ---- epilogue: out = d[b,o] * acc ----
#pragma unroll
  for (int m = 0; m < 8; ++m) {
#pragma unroll
    for (int n = 0; n < 4; ++n) {
#pragma unroll
      for (int j = 0; j < 4; ++j) {
        int o_l = wr * 128 + m * 16 + (lane >> 4) * 4 + j;
        int o = ot * 256 + o_l;
        int yy = sp * 4 + wc;
        int cx = n * 16 + l15;
        out[(((size_t)b * COUT + o) * HH + yy) * WW + cx] = d_s[o_l] * acc[m][n][j];
      }
    }
  }
}

// ---------------- fallback conv (round-1 kernel) for small ws ----------------
__global__ __launch_bounds__(256) void k_conv_fb(const float* __restrict__ x,
                                                 const short* __restrict__ Wr,
                                                 const float* __restrict__ gamma,
                                                 const float* __restrict__ dscale,
                                                 float* __restrict__ out) {
  __shared__ short As[128 * 64];
  __shared__ short Xs[4 * 64 * 64];
  __shared__ float gam_s[CIN];
  __shared__ float d_s[128];

  const int sp = blockIdx.x;
  const int ot = blockIdx.y;
  const int b  = blockIdx.z;
  const int t  = threadIdx.x;
  const int lane = t & 63;
  const int wv = t >> 6;
  const int wr = wv >> 1;
  const int wc = wv & 1;

  gam_s[t] = gamma[b * CIN + t];
  gam_s[t + 256] = gamma[b * CIN + t + 256];
  if (t < 128) d_s[t] = dscale[b * COUT + ot * 128 + t];

  f32x4 acc[4][4];
#pragma unroll
  for (int m = 0; m < 4; ++m)
#pragma unroll
    for (int n = 0; n < 4; ++n)
      acc[m][n] = (f32x4){0.f, 0.f, 0.f, 0.f};

  const int srow = t >> 6;
  const int sc = t & 63;
  const int ysrc = sp * 2 + srow - 1;
  const bool rv = (ysrc >= 0) && (ysrc < HH);
  const int ycl = rv ? ysrc : 0;
  const float* xrow = x + (((size_t)b * CIN) * HH + ycl) * WW + sc;
  short* xs_base = &Xs[(srow * 64 + sc) * 64];
  const int xs_sw = (sc & 7) << 4;

  for (int chunk = 0; chunk < CIN / 64; ++chunk) {
    const int i0 = chunk * 64;
    __syncthreads();
    {
      const float* xp = xrow + (size_t)i0 * (HH * WW);
#pragma unroll
      for (int i8 = 0; i8 < 8; ++i8) {
        short tmp[8];
#pragma unroll
        for (int j = 0; j < 8; ++j) {
          int i = i8 * 8 + j;
          float v = rv ? xp[i * (HH * WW)] : 0.0f;
          tmp[j] = f2bf(v * gam_s[i0 + i]);
        }
        char* dst = (char*)xs_base + ((i8 * 16) ^ xs_sw);
        *reinterpret_cast<bf16x8*>(dst) = *reinterpret_cast<const bf16x8*>(tmp);
      }
    }
    for (int tap = 0; tap < TAPS; ++tap) {
      __syncthreads();
#pragma unroll
      for (int j = 0; j < 4; ++j) {
        int s = t + 256 * j;
        int row = s >> 3, sl = s & 7;
        int kbyte = (sl * 16) ^ ((row & 7) << 4);
        const short* src = Wr + ((size_t)(ot * 128 + row) * TAPS + tap) * CIN +
                           i0 + (kbyte >> 1);
        *reinterpret_cast<bf16x8*>((char*)As + row * 128 + sl * 16) =
            *reinterpret_cast<const bf16x8*>(src);
      }
      __syncthreads();

      const int dy = tap / 3 - 1, dx = tap % 3 - 1;
      bf16x8 afr[2][4], bfr[2][4];
#pragma unroll
      for (int kk = 0; kk < 2; ++kk) {
        const int kb = kk * 64 + (lane >> 4) * 16;
#pragma unroll
        for (int m = 0; m < 4; ++m) {
          int row = wr * 64 + m * 16 + (lane & 15);
          afr[kk][m] = *reinterpret_cast<const bf16x8*>(
              (const char*)As + row * 128 + (kb ^ ((row & 7) << 4)));
        }
#pragma unroll
        for (int n = 0; n < 4; ++n) {
          int p = wc * 64 + n * 16 + (lane & 15);
          int r = p >> 6, c = p & 63;
          int cc = c + dx;
          bool val = (cc >= 0) && (cc < WW);
          int ccl = val ? cc : 0;
          int rr = r + dy + 1;
          bf16x8 f = *reinterpret_cast<const bf16x8*>(
              (const char*)Xs + (rr * 64 + ccl) * 128 + (kb ^ ((ccl & 7) << 4)));
          if (!val) f = (bf16x8){0, 0, 0, 0, 0, 0, 0, 0};
          bfr[kk][n] = f;
        }
      }
#pragma unroll
      for (int m = 0; m < 4; ++m)
#pragma unroll
        for (int n = 0; n < 4; ++n)
#pragma unroll
          for (int kk = 0; kk < 2; ++kk)
            acc[m][n] = __builtin_amdgcn_mfma_f32_16x16x32_bf16(
                afr[kk][m], bfr[kk][n], acc[m][n], 0, 0, 0);
    }
  }

#pragma unroll
  for (int m = 0; m < 4; ++m) {
#pragma unroll
    for (int n = 0; n < 4; ++n) {
#pragma unroll
      for (int j = 0; j < 4; ++j) {
        int o_l = wr * 64 + m * 16 + (lane >> 4) * 4 + j;
        int o = ot * 128 + o_l;
        int p = wc * 64 + n * 16 + (lane & 15);
        int yy = sp * 2 + (p >> 6);
        int cx = p & 63;
        out[(((size_t)b * COUT + o) * HH + yy) * WW + cx] = d_s[o_l] * acc[m][n][j];
      }
    }
  }
}

extern "C" void kernel_launch(void* const* d_in, const int* in_sizes, int n_in,
                              void* d_out, int out_size, void* d_ws, size_t ws_size,
                              hipStream_t stream) {
  const float* x = (const float*)d_in[0];
  const float* y = (const float*)d_in[1];
  const float* w_conv = (const float*)d_in[2];
  const float* w_gamma = (const float*)d_in[3];
  const float* b_gamma = (const float*)d_in[4];
  float* out = (float*)d_out;

  char* ws = (char*)d_ws;
  short* W2 = (short*)ws;                        // 4,718,592 B (+pad)
  float* gamma = (float*)(ws + 4849664);         // 32,768 B
  float* dsc = (float*)(ws + 4882432);           // 32,768 B
  float* s2 = (float*)(ws + 4915200);            // 1,048,576 B
  char* zbuf = ws + 5963776;                     // 4,096 B zero page
  short* xm = (short*)(ws + 5967872);            // 67,108,864 B
  const size_t NEED = 5967872 + (size_t)NB * HH * WW * CIN * 2 + 4096;

  const bool fast = ws_size >= NEED;

  if (fast) {
    hipLaunchKernelGGL(k_gamma, dim3(NB), dim3(512), 0, stream, y, w_gamma,
                       b_gamma, gamma, (float*)zbuf);
    hipLaunchKernelGGL(k_prep2, dim3(COUT), dim3(256), 0, stream, w_conv, s2, W2);
    hipLaunchKernelGGL(k_d, dim3(NB), dim3(512), 0, stream, gamma, s2, dsc);
    hipLaunchKernelGGL(k_xmod2, dim3(HH, NB), dim3(256), 0, stream, x, gamma, xm);
    hipLaunchKernelGGL(k_conv6, dim3(512), dim3(512), 0, stream, xm, W2,
                       (const short*)zbuf, dsc, out);
  } else {
    hipLaunchKernelGGL(k_gamma, dim3(NB), dim3(512), 0, stream, y, w_gamma,
                       b_gamma, gamma, (float*)nullptr);
    hipLaunchKernelGGL(k_prep, dim3(COUT), dim3(256), 0, stream, w_conv, s2, W2);
    hipLaunchKernelGGL(k_d, dim3(NB), dim3(512), 0, stream, gamma, s2, dsc);
    hipLaunchKernelGGL(k_conv_fb, dim3(32, 4, NB), dim3(256), 0, stream, x, W2,
                       gamma, dsc, out);
  }
}